// Round 15
// baseline (60.427 us; speedup 1.0000x reference)
//
#include <hip/hip_runtime.h>
#include <hip/hip_bf16.h>

// Problem constants (DynamicGraphPruning: B=8, H=W=128, C=256, PROJ=128)
#define Bn   8
#define Ln   16384     // H*W
#define Cn   256
#define Pn   128       // PROJ
#define En   65024     // 4*127*128 grid edges
#define Qn   16256     // 127*128 edges per direction-quarter
#define LN_EPSf 1e-5f
#define NTILES 4096    // 32-row proj tiles
#define PGRID  768     // persistent proj grid (3 blocks/CU)

typedef __attribute__((ext_vector_type(8)))  short short8;  // bf16x8 MFMA frag
typedef __attribute__((ext_vector_type(16))) float f32x16;  // 32x32 accum frag

__device__ __forceinline__ float bf2f(unsigned short u) {
    union { unsigned int i; float f; } v;
    v.i = ((unsigned int)u) << 16;
    return v.f;
}
__device__ __forceinline__ unsigned short f2bf(float x) {
    __hip_bfloat16 h = __float2bfloat16(x);   // RNE
    return *reinterpret_cast<unsigned short*>(&h);
}
__device__ __forceinline__ unsigned int pack2(float a, float b) {
    return (unsigned int)f2bf(a) | ((unsigned int)f2bf(b) << 16);
}

// lgkm-only barrier (never drains vmcnt -> keeps prefetch loads in flight)
#define BAR_LGKM do { \
    asm volatile("s_waitcnt lgkmcnt(0)" ::: "memory"); \
    __builtin_amdgcn_sched_barrier(0); \
    __builtin_amdgcn_s_barrier(); } while (0)
// counted barrier: leave the 8 newest vmem ops (next tile's loads) in flight
#define BAR_VM8 do { \
    asm volatile("s_waitcnt vmcnt(8) lgkmcnt(0)" ::: "memory"); \
    __builtin_amdgcn_sched_barrier(0); \
    __builtin_amdgcn_s_barrier(); } while (0)

// ---------------------------------------------------------------------------
// Per-tile proj compute: MFMA + LN + L2norm + transpose-store.
// All internal barriers lgkm-only so prefetch loads stay in flight.
__device__ __forceinline__ void tile_compute(
    char* fb, size_t row0, const short8* afrag, const float* plds,
    float (*red1)[32][2], float (*red2)[32],
    __hip_bfloat16* __restrict__ sem, int t, int w, int lane, int rl, int kh)
{
    const char* fbc = fb + rl * 512;
    const int   s   = rl & 7;
    f32x16 acc = (f32x16)0.f;
#pragma unroll
    for (int ks = 0; ks < 16; ks++) {
        const short8 bfv = *(const short8*)(fbc + (((2 * ks + kh) ^ s) << 4));
        acc = __builtin_amdgcn_mfma_f32_32x32x16_bf16(afrag[ks], bfv, acc, 0, 0, 0);
    }
    // lane (rl,kh): acc[r] = h[row0+rl][p = 32w + (r&3) + 8(r>>2) + 4kh]

    float s1 = 0.f, q1 = 0.f;
#pragma unroll
    for (int rq = 0; rq < 4; rq++) {
        const int p0 = 32 * w + 8 * rq + 4 * kh;
        const float4 b4 = *(const float4*)(plds + p0);
#pragma unroll
        for (int j = 0; j < 4; j++) {
            const float h = acc[rq * 4 + j] + ((const float*)&b4)[j];
            acc[rq * 4 + j] = h; s1 += h; q1 += h * h;
        }
    }
    s1 += __shfl_xor(s1, 32);
    q1 += __shfl_xor(q1, 32);
    if (lane < 32) { red1[w][rl][0] = s1; red1[w][rl][1] = q1; }
    BAR_LGKM;                                            // B1

    float st = 0.f, qt = 0.f;
#pragma unroll
    for (int i = 0; i < 4; i++) { st += red1[i][rl][0]; qt += red1[i][rl][1]; }
    const float mu  = st * (1.f / Pn);
    const float inv = rsqrtf(qt * (1.f / Pn) - mu * mu + LN_EPSf);

    float q2 = 0.f;
#pragma unroll
    for (int rq = 0; rq < 4; rq++) {
        const int p0 = 32 * w + 8 * rq + 4 * kh;
        const float4 g4 = *(const float4*)(plds + 128 + p0);
        const float4 e4 = *(const float4*)(plds + 256 + p0);
#pragma unroll
        for (int j = 0; j < 4; j++) {
            const float hn = (acc[rq * 4 + j] - mu) * inv
                           * ((const float*)&g4)[j] + ((const float*)&e4)[j];
            acc[rq * 4 + j] = hn; q2 += hn * hn;
        }
    }
    q2 += __shfl_xor(q2, 32);
    if (lane < 32) red2[w][rl] = q2;
    BAR_LGKM;                                            // B2

    float qs = 0.f;
#pragma unroll
    for (int i = 0; i < 4; i++) qs += red2[i][rl];
    const float rin = 1.f / fmaxf(sqrtf(qs), 1e-12f);

    // transpose through fb (its MFMA reads are all pre-B1), then coalesced
#pragma unroll
    for (int rq = 0; rq < 4; rq++) {
        uint2 val;
        val.x = pack2(acc[rq * 4 + 0] * rin, acc[rq * 4 + 1] * rin);
        val.y = pack2(acc[rq * 4 + 2] * rin, acc[rq * 4 + 3] * rin);
        *(uint2*)(fb + rl * 256 + (((4 * w + rq) ^ (rl & 7)) << 4)
                  + (kh << 3)) = val;
    }
    BAR_LGKM;                                            // B3

#pragma unroll
    for (int i = 0; i < 2; i++) {
        const int r = (t >> 4) + i * 16;
        const int G = t & 15;
        const uint4 v = *(const uint4*)(fb + r * 256 + ((G ^ (r & 7)) << 4));
        *reinterpret_cast<uint4*>(sem + (row0 + r) * Pn + G * 8) = v;
    }
}

// ---------------------------------------------------------------------------
// Kernel 1: PERSISTENT proj (r15): 768 blocks grid-stride over 4096 tiles.
// Prologue builds afrag directly from Wp (each W element read once per block,
// coalesced across lanes, L2-hot after the first wave of blocks) -> no
// wt_prep kernel, no Wt2 buffer. Per tile: {stage | prefetch-next | vm8-bar
// | compute}, all LN barriers lgkm-only (prefetch rides through).
__global__ __launch_bounds__(256, 3)
void proj_persist(const float* __restrict__ F, const float* __restrict__ Wp,
                  const float* __restrict__ bp, const float* __restrict__ gam,
                  const float* __restrict__ bet, __hip_bfloat16* __restrict__ sem)
{
    __shared__ char  fbuf[2][32 * 512]; // 2 x 16 KB bf16 [row][g16^(row&7)][16B]
    __shared__ float red1[4][32][2];
    __shared__ float red2[4][32];
    __shared__ float plds[384];         // bp | gam | bet

    const int t    = threadIdx.x;
    const int bid  = blockIdx.x;
    const int w    = t >> 6;            // wave 0..3 = p-quarter
    const int lane = t & 63;
    const int rl   = lane & 31;         // feature row within tile (D col)
    const int kh   = lane >> 5;         // k-half within 16-k step

    // ---- issue first tile's F loads immediately (start HBM)
    float4 sg[8];
    int tile = bid;
    {
        const float* base = F + (size_t)tile * 32 * Cn;
#pragma unroll
        for (int j = 0; j < 8; j++)
            sg[j] = *(const float4*)(base + j * 1024 + w * 256 + lane * 4);
    }

    // ---- params to LDS
    for (int i = t; i < 384; i += 256)
        plds[i] = (i < 128) ? bp[i] : (i < 256) ? gam[i - 128] : bet[i - 256];

    // ---- afrag built directly from Wp: thread (w,rl,kh) owns column 32w+rl,
    // c = (2ks+kh)*8 + j. Lanes rl=0..31 read consecutive p -> coalesced.
    short8 afrag[16];
    {
        const float* wcol = Wp + 32 * w + rl;
#pragma unroll
        for (int ks = 0; ks < 16; ks++) {
            const int c0 = (2 * ks + kh) * 8;
            short8 v;
#pragma unroll
            for (int j = 0; j < 8; j++)
                v[j] = (short)f2bf(wcol[(size_t)(c0 + j) * Pn]);
            afrag[ks] = v;
        }
    }

    int cur = 0;
    for (; tile < NTILES; tile += PGRID) {
        // stage current tile (compiler waits only these sg loads)
#pragma unroll
        for (int j = 0; j < 8; j++) {
            const int r = j * 4 + w;
            uint2 v;
            v.x = pack2(sg[j].x, sg[j].y);
            v.y = pack2(sg[j].z, sg[j].w);
            *(uint2*)(fbuf[cur] + r * 512 + (((lane >> 1) ^ (r & 7)) << 4)
                      + ((lane & 1) << 3)) = v;
        }
        __builtin_amdgcn_sched_barrier(0);   // pin: stage above, prefetch below

        // prefetch next tile for this block (8 newest vmem ops at the bar)
        const int nt = tile + PGRID;
        if (nt < NTILES) {
            const float* base = F + (size_t)nt * 32 * Cn;
#pragma unroll
            for (int j = 0; j < 8; j++)
                sg[j] = *(const float4*)(base + j * 1024 + w * 256 + lane * 4);
        }

        BAR_VM8;     // tile ready; prefetch + older stores ride through

        tile_compute(fbuf[cur], (size_t)tile * 32, afrag, plds,
                     red1, red2, sem, t, w, lane, rl, kh);
        cur ^= 1;
    }
}

// ---------------------------------------------------------------------------
// Kernel 2: per-edge semantic dot + spatial sim; outputs FLOAT32.
// Span-fused (r13-proven): one block owns 32 consecutive dst nodes, computes
// both vertical (src=d+128) and horizontal (src=d+1) edges; twins mirrored.
__global__ __launch_bounds__(256)
void edge_kernel(const __hip_bfloat16* __restrict__ sem,
                 const float* __restrict__ coords,
                 const float* __restrict__ alpha,
                 float* __restrict__ out_idx,
                 float* __restrict__ out_w)
{
    const int t    = threadIdx.x;
    const int slot = t >> 2;            // 0..63: 0-31 vertical, 32-63 horizontal
    const int sub  = t & 3;
    const int n0g  = blockIdx.x * 32;   // global dst base
    const int b    = n0g >> 14;         // / Ln
    const int n0   = n0g & (Ln - 1);
    const int i    = slot & 31;
    const bool hor = slot >= 32;
    const int d    = n0 + i;            // dst node (local)

    bool valid; int s;
    if (!hor) { valid = d < (Ln - 128);    s = valid ? d + 128 : d; }
    else      { valid = (d & 127) != 127;  s = valid ? d + 1   : d; }

    const short* base = (const short*)sem + (size_t)b * Ln * Pn;
    const short* srow = base + (size_t)s * Pn + sub * 8;   // element offset
    const short* drow = base + (size_t)d * Pn + sub * 8;

    float dot = 0.f;
#pragma unroll
    for (int j = 0; j < 4; j++) {       // elements sub*8 + j*32 .. +7
        const short8 a = *(const short8*)(srow + j * 32);
        const short8 c = *(const short8*)(drow + j * 32);
#pragma unroll
        for (int k = 0; k < 8; k++)
            dot = fmaf(bf2f((unsigned short)a[k]), bf2f((unsigned short)c[k]), dot);
    }
    dot += __shfl_xor(dot, 1);
    dot += __shfl_xor(dot, 2);

    if (sub == 0 && valid) {
        const float a = 1.f / (1.f + expf(-alpha[0]));
        const size_t sc = ((size_t)b * Ln + s) * 2;
        const size_t dc = ((size_t)b * Ln + d) * 2;
        const float ddx = coords[sc + 0] - coords[dc + 0];
        const float ddy = coords[sc + 1] - coords[dc + 1];
        const float dist = sqrtf(ddx * ddx + ddy * ddy + 1e-8f);
        const float ssim = 1.f - dist / 1.414f;
        const float wgt  = a * dot + (1.f - a) * ssim;

        size_t gidx;
        if (!hor) gidx = (size_t)b * En + d;                       // quarter 0
        else      gidx = (size_t)b * En + 2 * Qn + (d - (d >> 7)); // quarter 2

        out_w[gidx]      = wgt;
        out_w[gidx + Qn] = wgt;                                    // twin
        float2 fw; fw.x = (float)s; fw.y = (float)d;
        float2 tw; tw.x = (float)d; tw.y = (float)s;
        *reinterpret_cast<float2*>(out_idx + gidx * 2)        = fw;
        *reinterpret_cast<float2*>(out_idx + (gidx + Qn) * 2) = tw;
    }
}

extern "C" void kernel_launch(void* const* d_in, const int* in_sizes, int n_in,
                              void* d_out, int out_size, void* d_ws, size_t ws_size,
                              hipStream_t stream) {
    const float* F      = (const float*)d_in[0];   // (B,L,C)
    const float* coords = (const float*)d_in[1];   // (B,L,2)
    const float* alpha  = (const float*)d_in[3];   // scalar
    const float* Wp     = (const float*)d_in[4];   // (C,P)
    const float* bp     = (const float*)d_in[5];   // (P,)
    const float* gam    = (const float*)d_in[6];   // (P,)
    const float* bet    = (const float*)d_in[7];   // (P,)

    float* out     = (float*)d_out;                 // f32 outputs, concat order:
    float* out_idx = out;                           // edge_index (B,E,2) as f32
    float* out_w   = out + (size_t)Bn * En * 2;     // edge_weights (B,E) as f32

    __hip_bfloat16* sem = (__hip_bfloat16*)d_ws;    // 32 MB scratch

    proj_persist<<<PGRID, 256, 0, stream>>>(F, Wp, bp, gam, bet, sem);
    edge_kernel<<<(Bn * Ln) / 32, 256, 0, stream>>>(sem, coords, alpha,
                                                    out_idx, out_w);
}

// Round 16
// 54.902 us; speedup vs baseline: 1.1006x; 1.1006x over previous
//
#include <hip/hip_runtime.h>
#include <hip/hip_bf16.h>

// Problem constants (DynamicGraphPruning: B=8, H=W=128, C=256, PROJ=128)
#define Bn   8
#define Ln   16384     // H*W
#define Cn   256
#define Pn   128       // PROJ
#define En   65024     // 4*127*128 grid edges
#define Qn   16256     // 127*128 edges per direction-quarter
#define LN_EPSf 1e-5f

typedef __attribute__((ext_vector_type(8)))  short short8;  // bf16x8 MFMA frag
typedef __attribute__((ext_vector_type(16))) float f32x16;  // 32x32 accum frag

__device__ __forceinline__ float bf2f(unsigned short u) {
    union { unsigned int i; float f; } v;
    v.i = ((unsigned int)u) << 16;
    return v.f;
}
__device__ __forceinline__ unsigned short f2bf(float x) {
    __hip_bfloat16 h = __float2bfloat16(x);   // RNE
    return *reinterpret_cast<unsigned short*>(&h);
}
__device__ __forceinline__ unsigned int pack2(float a, float b) {
    return (unsigned int)f2bf(a) | ((unsigned int)f2bf(b) << 16);
}

// lgkm-only barrier (never drains vmcnt -> keeps prefetch loads in flight)
#define BAR_LGKM do { \
    asm volatile("s_waitcnt lgkmcnt(0)" ::: "memory"); \
    __builtin_amdgcn_sched_barrier(0); \
    __builtin_amdgcn_s_barrier(); } while (0)
// counted barrier: leave the 8 newest vmem ops (tile-1 sg loads) outstanding
#define BAR_VM8 do { \
    asm volatile("s_waitcnt vmcnt(8) lgkmcnt(0)" ::: "memory"); \
    __builtin_amdgcn_sched_barrier(0); \
    __builtin_amdgcn_s_barrier(); } while (0)

// ---------------------------------------------------------------------------
// Kernel 0: Wp (C x P, f32) -> Wt2 k-granule-major bf16: Wt2[g=c/8][p][8]
__global__ __launch_bounds__(256)
void wt_prep(const float* __restrict__ W, __hip_bfloat16* __restrict__ Wt2)
{
    const int u = blockIdx.x * 256 + threadIdx.x;   // 0..4095
    const int p = u & 127;
    const int g = u >> 7;
    short8 v;
#pragma unroll
    for (int j = 0; j < 8; j++)
        v[j] = (short)f2bf(W[(size_t)(g * 8 + j) * Pn + p]);
    *(short8*)((short*)Wt2 + (size_t)u * 8) = v;
}

// ---------------------------------------------------------------------------
// Per-tile compute: MFMA + LN + L2norm + transpose-store. All barriers
// lgkm-only, so a prefetch issued before entry stays in flight.
__device__ __forceinline__ void tile_compute(
    char* fb, size_t row0, const short8* afrag, const float* plds,
    float (*red1)[32][2], float (*red2)[32],
    __hip_bfloat16* __restrict__ sem, int t, int w, int lane, int rl, int kh)
{
    const char* fbc = fb + rl * 512;
    const int   s   = rl & 7;
    f32x16 acc = (f32x16)0.f;
#pragma unroll
    for (int ks = 0; ks < 16; ks++) {
        const short8 bfv = *(const short8*)(fbc + (((2 * ks + kh) ^ s) << 4));
        acc = __builtin_amdgcn_mfma_f32_32x32x16_bf16(afrag[ks], bfv, acc, 0, 0, 0);
    }
    // lane (rl,kh): acc[r] = h[row0+rl][p = 32w + (r&3) + 8(r>>2) + 4kh]

    float s1 = 0.f, q1 = 0.f;
#pragma unroll
    for (int rq = 0; rq < 4; rq++) {
        const int p0 = 32 * w + 8 * rq + 4 * kh;
        const float4 b4 = *(const float4*)(plds + p0);
#pragma unroll
        for (int j = 0; j < 4; j++) {
            const float h = acc[rq * 4 + j] + ((const float*)&b4)[j];
            acc[rq * 4 + j] = h; s1 += h; q1 += h * h;
        }
    }
    s1 += __shfl_xor(s1, 32);
    q1 += __shfl_xor(q1, 32);
    if (lane < 32) { red1[w][rl][0] = s1; red1[w][rl][1] = q1; }
    BAR_LGKM;                                            // B1

    float st = 0.f, qt = 0.f;
#pragma unroll
    for (int i = 0; i < 4; i++) { st += red1[i][rl][0]; qt += red1[i][rl][1]; }
    const float mu  = st * (1.f / Pn);
    const float inv = rsqrtf(qt * (1.f / Pn) - mu * mu + LN_EPSf);

    float q2 = 0.f;
#pragma unroll
    for (int rq = 0; rq < 4; rq++) {
        const int p0 = 32 * w + 8 * rq + 4 * kh;
        const float4 g4 = *(const float4*)(plds + 128 + p0);
        const float4 e4 = *(const float4*)(plds + 256 + p0);
#pragma unroll
        for (int j = 0; j < 4; j++) {
            const float hn = (acc[rq * 4 + j] - mu) * inv
                           * ((const float*)&g4)[j] + ((const float*)&e4)[j];
            acc[rq * 4 + j] = hn; q2 += hn * hn;
        }
    }
    q2 += __shfl_xor(q2, 32);
    if (lane < 32) red2[w][rl] = q2;
    BAR_LGKM;                                            // B2

    float qs = 0.f;
#pragma unroll
    for (int i = 0; i < 4; i++) qs += red2[i][rl];
    const float rin = 1.f / fmaxf(sqrtf(qs), 1e-12f);

    // transpose through fb (its MFMA reads are all pre-B1), then coalesced
#pragma unroll
    for (int rq = 0; rq < 4; rq++) {
        uint2 val;
        val.x = pack2(acc[rq * 4 + 0] * rin, acc[rq * 4 + 1] * rin);
        val.y = pack2(acc[rq * 4 + 2] * rin, acc[rq * 4 + 3] * rin);
        *(uint2*)(fb + rl * 256 + (((4 * w + rq) ^ (rl & 7)) << 4)
                  + (kh << 3)) = val;
    }
    BAR_LGKM;                                            // B3

#pragma unroll
    for (int i = 0; i < 2; i++) {
        const int r = (t >> 4) + i * 16;
        const int G = t & 15;
        const uint4 v = *(const uint4*)(fb + r * 256 + ((G ^ (r & 7)) << 4));
        *reinterpret_cast<uint4*>(sem + (row0 + r) * Pn + G * 8) = v;
    }
}

// ---------------------------------------------------------------------------
// Kernel 1: h = F @ W + b; LayerNorm; L2-normalize -> sem (bf16).
// r13 config (measured session best): TWO tiles per block with cross-tile reg
// prefetch. Tile-1's global loads are issued before tile-0's B0 barrier,
// which waits vmcnt(8) only -> tile-1's HBM latency hides under tile-0's
// compute+epilogue. afrag/params prologue amortized over 2 tiles.
__global__ __launch_bounds__(256, 3)
void proj_tile(const float* __restrict__ F,
               const __hip_bfloat16* __restrict__ Wt2,
               const float* __restrict__ bp, const float* __restrict__ gam,
               const float* __restrict__ bet, __hip_bfloat16* __restrict__ sem)
{
    __shared__ char  fbuf[2][32 * 512]; // 2 x 16 KB bf16 [row][g16^(row&7)][16B]
    __shared__ float red1[4][32][2];
    __shared__ float red2[4][32];
    __shared__ float plds[384];         // bp | gam | bet

    const int t    = threadIdx.x;
    const int w    = t >> 6;            // wave 0..3 = p-quarter
    const int lane = t & 63;
    const int rl   = lane & 31;         // feature row within tile (D col)
    const int kh   = lane >> 5;         // k-half within 16-k step
    const size_t row0 = (size_t)blockIdx.x * 64;

    // ---- issue tile-0 F loads (8 x 1KB-contiguous per wave)
    float4 sg[8];
    {
        const float* base = F + row0 * Cn;
#pragma unroll
        for (int j = 0; j < 8; j++)
            sg[j] = *(const float4*)(base + j * 1024 + w * 256 + lane * 4);
    }

    // ---- params to LDS
    for (int i = t; i < 384; i += 256)
        plds[i] = (i < 128) ? bp[i] : (i < 256) ? gam[i - 128] : bet[i - 256];

    // ---- afrag loads (issued BEFORE tile-1 sg so vmcnt(8) leaves only sg1)
    short8 afrag[16];
#pragma unroll
    for (int ks = 0; ks < 16; ks++)
        afrag[ks] = *((const short8*)Wt2 + (2 * ks + kh) * 128 + 32 * w + rl);

    // ---- convert + stage tile 0 (compiler waits only the sg0 loads)
#pragma unroll
    for (int j = 0; j < 8; j++) {
        const int r = j * 4 + w;
        uint2 v;
        v.x = pack2(sg[j].x, sg[j].y);
        v.y = pack2(sg[j].z, sg[j].w);
        *(uint2*)(fbuf[0] + r * 512 + (((lane >> 1) ^ (r & 7)) << 4)
                  + ((lane & 1) << 3)) = v;
    }
    __builtin_amdgcn_sched_barrier(0);   // pin: afrag/stage above, sg1 below

    // ---- issue tile-1 F loads (the 8 newest vmem ops at B0)
    {
        const float* base = F + (row0 + 32) * Cn;
#pragma unroll
        for (int j = 0; j < 8; j++)
            sg[j] = *(const float4*)(base + j * 1024 + w * 256 + lane * 4);
    }

    BAR_VM8;                             // B0: tile0+params+afrag ready; sg1 in flight

    tile_compute(fbuf[0], row0, afrag, plds, red1, red2, sem, t, w, lane, rl, kh);

    // ---- stage tile 1 (compiler waits sg1 loads, long since landed)
#pragma unroll
    for (int j = 0; j < 8; j++) {
        const int r = j * 4 + w;
        uint2 v;
        v.x = pack2(sg[j].x, sg[j].y);
        v.y = pack2(sg[j].z, sg[j].w);
        *(uint2*)(fbuf[1] + r * 512 + (((lane >> 1) ^ (r & 7)) << 4)
                  + ((lane & 1) << 3)) = v;
    }
    BAR_LGKM;                            // B0' (doesn't drain tile-0 sem stores)

    tile_compute(fbuf[1], row0 + 32, afrag, plds, red1, red2, sem, t, w, lane, rl, kh);
}

// ---------------------------------------------------------------------------
// Kernel 2: per-edge semantic dot + spatial sim; outputs FLOAT32.
// Span-fused: one block owns 32 consecutive dst nodes and computes BOTH
// their vertical (src=d+128) and horizontal (src=d+1) edges -> each sem row
// fetched ~once per block instead of by 4 scattered blocks. 4 lanes/edge,
// 64 B/lane, full-cache-line coalesced. Twins (quarters 1,3) mirrored.
__global__ __launch_bounds__(256)
void edge_kernel(const __hip_bfloat16* __restrict__ sem,
                 const float* __restrict__ coords,
                 const float* __restrict__ alpha,
                 float* __restrict__ out_idx,
                 float* __restrict__ out_w)
{
    const int t    = threadIdx.x;
    const int slot = t >> 2;            // 0..63: 0-31 vertical, 32-63 horizontal
    const int sub  = t & 3;
    const int n0g  = blockIdx.x * 32;   // global dst base
    const int b    = n0g >> 14;         // / Ln
    const int n0   = n0g & (Ln - 1);
    const int i    = slot & 31;
    const bool hor = slot >= 32;
    const int d    = n0 + i;            // dst node (local)

    bool valid; int s;
    if (!hor) { valid = d < (Ln - 128);    s = valid ? d + 128 : d; }
    else      { valid = (d & 127) != 127;  s = valid ? d + 1   : d; }

    const short* base = (const short*)sem + (size_t)b * Ln * Pn;
    const short* srow = base + (size_t)s * Pn + sub * 8;   // element offset
    const short* drow = base + (size_t)d * Pn + sub * 8;

    float dot = 0.f;
#pragma unroll
    for (int j = 0; j < 4; j++) {       // elements sub*8 + j*32 .. +7
        const short8 a = *(const short8*)(srow + j * 32);
        const short8 c = *(const short8*)(drow + j * 32);
#pragma unroll
        for (int k = 0; k < 8; k++)
            dot = fmaf(bf2f((unsigned short)a[k]), bf2f((unsigned short)c[k]), dot);
    }
    dot += __shfl_xor(dot, 1);
    dot += __shfl_xor(dot, 2);

    if (sub == 0 && valid) {
        const float a = 1.f / (1.f + expf(-alpha[0]));
        const size_t sc = ((size_t)b * Ln + s) * 2;
        const size_t dc = ((size_t)b * Ln + d) * 2;
        const float ddx = coords[sc + 0] - coords[dc + 0];
        const float ddy = coords[sc + 1] - coords[dc + 1];
        const float dist = sqrtf(ddx * ddx + ddy * ddy + 1e-8f);
        const float ssim = 1.f - dist / 1.414f;
        const float wgt  = a * dot + (1.f - a) * ssim;

        size_t gidx;
        if (!hor) gidx = (size_t)b * En + d;                       // quarter 0
        else      gidx = (size_t)b * En + 2 * Qn + (d - (d >> 7)); // quarter 2

        out_w[gidx]      = wgt;
        out_w[gidx + Qn] = wgt;                                    // twin
        float2 fw; fw.x = (float)s; fw.y = (float)d;
        float2 tw; tw.x = (float)d; tw.y = (float)s;
        *reinterpret_cast<float2*>(out_idx + gidx * 2)        = fw;
        *reinterpret_cast<float2*>(out_idx + (gidx + Qn) * 2) = tw;
    }
}

extern "C" void kernel_launch(void* const* d_in, const int* in_sizes, int n_in,
                              void* d_out, int out_size, void* d_ws, size_t ws_size,
                              hipStream_t stream) {
    const float* F      = (const float*)d_in[0];   // (B,L,C)
    const float* coords = (const float*)d_in[1];   // (B,L,2)
    const float* alpha  = (const float*)d_in[3];   // scalar
    const float* Wp     = (const float*)d_in[4];   // (C,P)
    const float* bp     = (const float*)d_in[5];   // (P,)
    const float* gam    = (const float*)d_in[6];   // (P,)
    const float* bet    = (const float*)d_in[7];   // (P,)

    float* out     = (float*)d_out;                 // f32 outputs, concat order:
    float* out_idx = out;                           // edge_index (B,E,2) as f32
    float* out_w   = out + (size_t)Bn * En * 2;     // edge_weights (B,E) as f32

    __hip_bfloat16* Wt2 = (__hip_bfloat16*)d_ws;               // 64 KB
    __hip_bfloat16* sem = (__hip_bfloat16*)((char*)d_ws + Cn * Pn * 2); // 32 MB

    wt_prep<<<16, 256, 0, stream>>>(Wp, Wt2);
    proj_tile<<<(Bn * Ln) / 64, 256, 0, stream>>>(F, Wt2, bp, gam, bet, sem);
    edge_kernel<<<(Bn * Ln) / 32, 256, 0, stream>>>(sem, coords, alpha,
                                                    out_idx, out_w);
}